// Round 9
// baseline (260.970 us; speedup 1.0000x reference)
//
#include <hip/hip_runtime.h>
#include <hip/hip_bf16.h>
#include <hip/hip_fp16.h>
#include <math.h>

#define BATCH 32
#define INC 1024
#define MIDC 256
#define SC 256
#define HW 784
#define ROWS 25088   // BATCH*HW
#define KSEL 196     // int(0.25 * 784)

typedef _Float16 f16;
typedef __attribute__((ext_vector_type(8))) _Float16 hfrag;  // 8 fp16 (4 VGPRs)
typedef __attribute__((ext_vector_type(4))) float f4;        // 4 fp32 acc

struct alignas(8) h4s { f16 x, y, z, w; };

__device__ inline float stanh_fast(float p) {
    // 1.7159*tanh(2p/3) = 1.7159*(1 - 2/(exp(4p/3)+1))
    float e = __expf(1.33333333f * p);
    return 1.7159f * (1.0f - 2.0f / (e + 1.0f));
}

// ---------------- fp32 -> fp16 weight convert (layout preserved) -----------
__global__ __launch_bounds__(256) void cvt_f16(const float* __restrict__ src,
                                               f16* __restrict__ dst, int n4) {
    int i = blockIdx.x * 256 + threadIdx.x;
    if (i >= n4) return;
    float4 v = ((const float4*)src)[i];
    h4s h = { (f16)v.x, (f16)v.y, (f16)v.z, (f16)v.w };
    ((h4s*)dst)[i] = h;
}

// ---------------- transpose x[b][c][n] -> xt[b][n][c] as fp16 --------------
__global__ __launch_bounds__(256) void prep_x(const float* __restrict__ x,
                                              f16* __restrict__ xh) {
    int b = blockIdx.z, c0 = blockIdx.y * 32, n0 = blockIdx.x * 32;
    __shared__ float tile[32][33];
    int t = threadIdx.x;
    int r = t >> 3, cg = (t & 7) * 4;
    if (n0 + cg + 3 < HW) {
        float4 v = *(const float4*)(x + (size_t)(b * INC + c0 + r) * HW + n0 + cg);
        tile[r][cg + 0] = v.x; tile[r][cg + 1] = v.y;
        tile[r][cg + 2] = v.z; tile[r][cg + 3] = v.w;
    }
    __syncthreads();
    int rn = t >> 3, cg2 = (t & 7) * 4;
    int n = n0 + rn;
    if (n < HW) {
        h4s h = { (f16)tile[cg2 + 0][rn], (f16)tile[cg2 + 1][rn],
                  (f16)tile[cg2 + 2][rn], (f16)tile[cg2 + 3][rn] };
        *(h4s*)(xh + ((size_t)b * HW + n) * INC + c0 + cg2) = h;
    }
}

// ---------------- u[b][m] = Wq_b[m] + Uq·s ---------------------------------
__global__ __launch_bounds__(256) void calc_u(const float* __restrict__ s,
                                              const float* __restrict__ Uq_w,
                                              const float* __restrict__ Wq_b,
                                              float* __restrict__ u) {
    __shared__ float ssh[SC];
    int b = blockIdx.x, m = threadIdx.x;
    ssh[m] = s[b * SC + m];
    __syncthreads();
    float acc = Wq_b[m];
    const float* uq = Uq_w + (size_t)m * SC;
    #pragma unroll 8
    for (int i = 0; i < SC; ++i) acc += ssh[i] * uq[i];
    u[b * MIDC + m] = acc;
}

// ---------------- GEMM1: sig_t[R][m] = stanh(Wq·xt[R] + u[R/784][m]) -------
__global__ __launch_bounds__(256) void gemm1_mfma(
    const f16* __restrict__ A,   // Wq [256][1024]
    const f16* __restrict__ B,   // xt [25088][1024]
    const float* __restrict__ u,
    f16* __restrict__ S) {       // sig [25088][256]
    const int R0 = blockIdx.x * 64;
    const int M0 = blockIdx.y * 128;
    __shared__ f16 Asm[128][40];
    __shared__ f16 Bsm[64][40];
    const int t = threadIdx.x;
    const int lane = t & 63, w = t >> 6;
    const int wc = (w >> 1) * 64;
    const int wr = (w & 1) * 32;
    const int ln = lane & 15, kg = lane >> 4;

    const int ar0 = t >> 2, ar1 = ar0 + 64;
    const int akc = (t & 3) * 8;
    const size_t aoff0 = (size_t)(M0 + ar0) * INC + akc;
    const size_t aoff1 = (size_t)(M0 + ar1) * INC + akc;
    const size_t boff  = (size_t)(R0 + ar0) * INC + akc;

    f4 acc[4][2];
    const f4 zero = {0.f, 0.f, 0.f, 0.f};
    #pragma unroll
    for (int i = 0; i < 4; ++i) { acc[i][0] = zero; acc[i][1] = zero; }

    hfrag rA0, rA1, rB;
    #define G1_LOAD(K0)                                   \
        rA0 = *(const hfrag*)(A + aoff0 + (K0));          \
        rA1 = *(const hfrag*)(A + aoff1 + (K0));          \
        rB  = *(const hfrag*)(B + boff  + (K0));

    G1_LOAD(0)
    for (int k0 = 0; k0 < INC; k0 += 32) {
        *(hfrag*)&Asm[ar0][akc] = rA0;
        *(hfrag*)&Asm[ar1][akc] = rA1;
        *(hfrag*)&Bsm[ar0][akc] = rB;
        __syncthreads();
        if (k0 + 32 < INC) { G1_LOAD(k0 + 32) }
        hfrag b0 = *(const hfrag*)&Bsm[wr + ln][kg * 8];
        hfrag b1 = *(const hfrag*)&Bsm[wr + 16 + ln][kg * 8];
        #pragma unroll
        for (int mi = 0; mi < 4; ++mi) {
            hfrag a = *(const hfrag*)&Asm[wc + mi * 16 + ln][kg * 8];
            acc[mi][0] = __builtin_amdgcn_mfma_f32_16x16x32_f16(a, b0, acc[mi][0], 0, 0, 0);
            acc[mi][1] = __builtin_amdgcn_mfma_f32_16x16x32_f16(a, b1, acc[mi][1], 0, 0, 0);
        }
        __syncthreads();
    }
    #undef G1_LOAD

    #pragma unroll
    for (int ni = 0; ni < 2; ++ni) {
        int R = R0 + wr + ni * 16 + ln;
        int b = R / HW;
        #pragma unroll
        for (int mi = 0; mi < 4; ++mi) {
            int mb = M0 + wc + mi * 16 + kg * 4;
            float uv[4];
            *(float4*)uv = *(const float4*)(u + b * MIDC + mb);
            h4s hv;
            hv.x = (f16)stanh_fast(acc[mi][ni][0] + uv[0]);
            hv.y = (f16)stanh_fast(acc[mi][ni][1] + uv[1]);
            hv.z = (f16)stanh_fast(acc[mi][ni][2] + uv[2]);
            hv.w = (f16)stanh_fast(acc[mi][ni][3] + uv[3]);
            *(h4s*)(S + (size_t)R * MIDC + mb) = hv;
        }
    }
}

// ---------------- FUSED GEMM2 + topk/softmax/dot ---------------------------
// Block = (b, 16 channels). GEMM phase: A/B frags straight from L2 (sig is
// 12.8 MB, cache-resident), alpha+bias -> LDS [16][788] f32 (never HBM).
// MFMA k-order identical to the old gemm2_mfma -> alpha bit-identical.
// Select phase: radix-select v3 per row from LDS (2 sub-histograms).
__global__ __launch_bounds__(256) void gemm2_topk(
    const f16* __restrict__ A,    // Ww [1024][256]
    const f16* __restrict__ B,    // sig [25088][256]
    const float* __restrict__ wb,
    const float* __restrict__ x,
    float* __restrict__ out) {
    const int b  = blockIdx.y;
    const int c0 = blockIdx.x * 16;
    const int t = threadIdx.x;
    const int lane = t & 63, w = t >> 6;
    const int ln = lane & 15, kg = lane >> 4;

    __shared__ float alpha[16][788];   // 50.4 KB
    __shared__ int hist[4][2][264];    // 8.25 KB; [wave][subgroup][bin(+pad)]

    // ---- GEMM phase (barrier-free per wave) ----
    hfrag a[8];
    #pragma unroll
    for (int k0 = 0; k0 < 8; ++k0)
        a[k0] = *(const hfrag*)(A + (size_t)(c0 + ln) * MIDC + k0 * 32 + kg * 8);
    float4 wv = *(const float4*)(wb + c0 + kg * 4);

    const int tstart = (w == 0) ? 0 : (13 + (w - 1) * 12);
    const int tcnt   = (w == 0) ? 13 : 12;     // 13+12+12+12 = 49 tiles
    const size_t Rbase = (size_t)b * HW;

    for (int ti = 0; ti < tcnt; ++ti) {
        const int nt = tstart + ti;
        const size_t boff = (Rbase + nt * 16 + ln) * MIDC + kg * 8;
        hfrag bb[8];
        #pragma unroll
        for (int k0 = 0; k0 < 8; ++k0)
            bb[k0] = *(const hfrag*)(B + boff + k0 * 32);
        f4 ac = {0.f, 0.f, 0.f, 0.f};
        #pragma unroll
        for (int k0 = 0; k0 < 8; ++k0)
            ac = __builtin_amdgcn_mfma_f32_16x16x32_f16(a[k0], bb[k0], ac, 0, 0, 0);
        #pragma unroll
        for (int r = 0; r < 4; ++r)
            alpha[4 * kg + r][nt * 16 + ln] = ac[r] + ((const float*)&wv)[r];
    }
    __syncthreads();

    // ---- select phase: wave w owns local rows {w, w+4, w+8, w+12} ----
    int* hp0 = &hist[w][0][0];
    const int g = lane >> 5;          // half-wave subgroup
    const bool has3 = (lane < 4);

    for (int rr = 0; rr < 4; ++rr) {
        const int cl  = w + rr * 4;
        const int row = b * INC + c0 + cl;
        float* arow = out + BATCH * INC + (size_t)row * HW;
        const float* xrow = x + (size_t)row * HW;
        const float4* lp = (const float4*)&alpha[cl][0];

        float4 v4[4];
        v4[0] = lp[lane];
        v4[1] = lp[lane + 64];
        v4[2] = lp[lane + 128];
        v4[3] = has3 ? lp[192 + lane] : make_float4(0.f, 0.f, 0.f, 0.f);

        const float* vv = (const float*)v4;
        uint32_t key[16];
        #pragma unroll
        for (int i = 0; i < 16; ++i) {
            bool ok = (i < 12) | has3;
            uint32_t uu = __float_as_uint(vv[i]);
            uint32_t k = (uu & 0x80000000u) ? ~uu : (uu | 0x80000000u);
            key[i] = ok ? k : 0u;
        }

        int kk = KSEL;
        uint32_t prefix = 0;
        uint32_t thkey = 0;
        bool done = false;

        #pragma unroll
        for (int round = 0; round < 4; ++round) {
            if (!done) {
                const int shift = 24 - 8 * round;
                const int4 z4 = {0, 0, 0, 0};
                if (round == 0) {
                    #pragma unroll
                    for (int j = 0; j < 3; ++j) {
                        int idx = lane + 64 * j;
                        if (idx < 132) ((int4*)hp0)[idx] = z4;
                    }
                    #pragma unroll
                    for (int i = 0; i < 16; ++i)
                        if (key[i]) atomicAdd(&hist[w][g][key[i] >> 24], 1);
                } else {
                    ((int4*)hp0)[lane] = z4;
                    const uint32_t himask = 0xFFFFFFFFu << (shift + 8);
                    #pragma unroll
                    for (int i = 0; i < 16; ++i)
                        if ((key[i] & himask) == prefix)
                            atomicAdd(&hp0[(key[i] >> shift) & 255], 1);
                }

                int h0, h1, h2, h3;
                if (round == 0) {
                    int4 ca = *(const int4*)&hist[w][0][4 * lane];
                    int4 cb = *(const int4*)&hist[w][1][4 * lane];
                    h0 = ca.x + cb.x; h1 = ca.y + cb.y;
                    h2 = ca.z + cb.z; h3 = ca.w + cb.w;
                } else {
                    int4 c = *(const int4*)&hp0[4 * lane];
                    h0 = c.x; h1 = c.y; h2 = c.z; h3 = c.w;
                }
                int gsum = h0 + h1 + h2 + h3;
                int suf = gsum;
                #pragma unroll
                for (int off = 1; off < 64; off <<= 1) {
                    int o = __shfl_down(suf, off, 64);
                    suf += (lane + off < 64) ? o : 0;
                }
                int ex = suf - gsum;
                int cgt3 = ex, cgt2 = cgt3 + h3, cgt1 = cgt2 + h2, cgt0 = cgt1 + h1;
                int bsel = -1, cg = 0, hs = 0;
                if (cgt0 < kk && kk <= cgt0 + h0) { bsel = 4 * lane + 0; cg = cgt0; hs = h0; }
                if (cgt1 < kk && kk <= cgt1 + h1) { bsel = 4 * lane + 1; cg = cgt1; hs = h1; }
                if (cgt2 < kk && kk <= cgt2 + h2) { bsel = 4 * lane + 2; cg = cgt2; hs = h2; }
                if (cgt3 < kk && kk <= cgt3 + h3) { bsel = 4 * lane + 3; cg = cgt3; hs = h3; }
                unsigned long long m = __ballot(bsel >= 0);
                int src = (int)__ffsll((long long)m) - 1;
                bsel = __shfl(bsel, src, 64);
                cg   = __shfl(cg,   src, 64);
                hs   = __shfl(hs,   src, 64);
                kk -= cg;
                prefix |= ((uint32_t)bsel) << shift;

                if (shift == 0) {
                    thkey = prefix;
                    done = true;
                } else if (kk == 1 || kk == hs) {
                    const uint32_t maskP = 0xFFFFFFFFu << shift;
                    bool want_max = (kk == 1);
                    uint32_t r = want_max ? 0u : 0xFFFFFFFFu;
                    #pragma unroll
                    for (int i = 0; i < 16; ++i) {
                        if ((key[i] & maskP) == prefix)
                            r = want_max ? (r > key[i] ? r : key[i])
                                         : (r < key[i] ? r : key[i]);
                    }
                    #pragma unroll
                    for (int off = 32; off; off >>= 1) {
                        uint32_t o = __shfl_xor(r, off, 64);
                        r = want_max ? (r > o ? r : o) : (r < o ? r : o);
                    }
                    thkey = r;
                    done = true;
                }
            }
        }

        uint32_t tu = (thkey & 0x80000000u) ? (thkey ^ 0x80000000u) : ~thkey;
        const float th = __uint_as_float(tu);

        float* vwp = (float*)v4;
        float mx = -INFINITY;
        #pragma unroll
        for (int i = 0; i < 16; ++i) {
            bool ok = (i < 12) | has3;
            float f = vwp[i];
            f = (f < th) ? 0.0f : f;
            vwp[i] = f;
            if (ok) mx = fmaxf(mx, f);
        }
        #pragma unroll
        for (int off = 32; off; off >>= 1) mx = fmaxf(mx, __shfl_xor(mx, off, 64));

        float sum = 0.f;
        #pragma unroll
        for (int i = 0; i < 16; ++i) {
            bool ok = (i < 12) | has3;
            float e = __expf(vwp[i] - mx);
            vwp[i] = e;
            sum += ok ? e : 0.f;
        }
        #pragma unroll
        for (int off = 32; off; off >>= 1) sum += __shfl_xor(sum, off, 64);
        float inv = 1.0f / sum;

        float dot = 0.f;
        {
            float4* ap = (float4*)arow;
            const float4* xp = (const float4*)xrow;
            #pragma unroll
            for (int ci = 0; ci < 4; ++ci) {
                if (ci == 3 && !has3) break;
                int chunk = (ci < 3) ? (lane + 64 * ci) : (192 + lane);
                float4 av;
                av.x = vwp[ci * 4 + 0] * inv;
                av.y = vwp[ci * 4 + 1] * inv;
                av.z = vwp[ci * 4 + 2] * inv;
                av.w = vwp[ci * 4 + 3] * inv;
                ap[chunk] = av;
                float4 xl = xp[chunk];
                dot += xl.x * av.x + xl.y * av.y + xl.z * av.z + xl.w * av.w;
            }
        }
        #pragma unroll
        for (int off = 32; off; off >>= 1) dot += __shfl_xor(dot, off, 64);
        if (lane == 0) out[row] = dot;
    }
}

extern "C" void kernel_launch(void* const* d_in, const int* in_sizes, int n_in,
                              void* d_out, int out_size, void* d_ws, size_t ws_size,
                              hipStream_t stream) {
    const float* x    = (const float*)d_in[0];
    const float* s    = (const float*)d_in[1];
    const float* Wq_w = (const float*)d_in[2];
    const float* Wq_b = (const float*)d_in[3];
    const float* Uq_w = (const float*)d_in[4];
    const float* w_w  = (const float*)d_in[5];
    const float* w_b  = (const float*)d_in[6];
    float* out = (float*)d_out;

    f16* xt   = (f16*)d_ws;                                   // [25088][1024]
    f16* sig  = xt + (size_t)ROWS * INC;                      // [25088][256]
    f16* wq_h = sig + (size_t)ROWS * MIDC;                    // [256][1024]
    f16* ww_h = wq_h + MIDC * INC;                            // [1024][256]
    float* u  = (float*)(ww_h + INC * MIDC);                  // [32][256]

    cvt_f16<<<256, 256, 0, stream>>>(Wq_w, wq_h, MIDC * INC / 4);
    cvt_f16<<<256, 256, 0, stream>>>(w_w, ww_h, INC * MIDC / 4);
    calc_u<<<BATCH, 256, 0, stream>>>(s, Uq_w, Wq_b, u);
    prep_x<<<dim3(25, 32, 32), 256, 0, stream>>>(x, xt);
    gemm1_mfma<<<dim3(ROWS / 64, 2), 256, 0, stream>>>(wq_h, xt, u, sig);
    gemm2_topk<<<dim3(INC / 16, BATCH), 256, 0, stream>>>(ww_h, sig, w_b, x, out);
}

// Round 10
// 177.606 us; speedup vs baseline: 1.4694x; 1.4694x over previous
//
#include <hip/hip_runtime.h>
#include <hip/hip_bf16.h>
#include <hip/hip_fp16.h>
#include <math.h>

#define BATCH 32
#define INC 1024
#define MIDC 256
#define SC 256
#define HW 784
#define ROWS 25088   // BATCH*HW
#define KSEL 196     // int(0.25 * 784)

typedef _Float16 f16;
typedef __attribute__((ext_vector_type(8))) _Float16 hfrag;  // 8 fp16 (4 VGPRs)
typedef __attribute__((ext_vector_type(4))) float f4;        // 4 fp32 acc

struct alignas(8) h4s { f16 x, y, z, w; };

__device__ inline float stanh_fast(float p) {
    // 1.7159*tanh(2p/3) = 1.7159*(1 - 2/(exp(4p/3)+1))
    float e = __expf(1.33333333f * p);
    return 1.7159f * (1.0f - 2.0f / (e + 1.0f));
}

// ---------------- prologue: cvt Wq, cvt Ww, calc_u in one launch -----------
__global__ __launch_bounds__(256) void prologue(
    const float* __restrict__ Wq_w, const float* __restrict__ w_w,
    const float* __restrict__ s, const float* __restrict__ Uq_w,
    const float* __restrict__ Wq_b,
    f16* __restrict__ wq_h, f16* __restrict__ ww_h, float* __restrict__ u) {
    __shared__ float ssh[SC];
    const int bid = blockIdx.x;
    const int t = threadIdx.x;
    if (bid < 256) {                       // Wq: 65536 float4 chunks
        int i = bid * 256 + t;
        float4 v = ((const float4*)Wq_w)[i];
        h4s h = { (f16)v.x, (f16)v.y, (f16)v.z, (f16)v.w };
        ((h4s*)wq_h)[i] = h;
    } else if (bid < 512) {                // Ww: 65536 float4 chunks
        int i = (bid - 256) * 256 + t;
        float4 v = ((const float4*)w_w)[i];
        h4s h = { (f16)v.x, (f16)v.y, (f16)v.z, (f16)v.w };
        ((h4s*)ww_h)[i] = h;
    } else {                               // calc_u: 32 blocks
        int b = bid - 512;
        ssh[t] = s[b * SC + t];
        __syncthreads();
        float acc = Wq_b[t];
        const float* uq = Uq_w + (size_t)t * SC;
        #pragma unroll 8
        for (int i = 0; i < SC; ++i) acc += ssh[i] * uq[i];
        u[b * MIDC + t] = acc;
    }
}

// ---------------- transpose x[b][c][n] -> xt[b][n][c] as fp16 --------------
__global__ __launch_bounds__(256) void prep_x(const float* __restrict__ x,
                                              f16* __restrict__ xh) {
    int b = blockIdx.z, c0 = blockIdx.y * 32, n0 = blockIdx.x * 32;
    __shared__ float tile[32][33];
    int t = threadIdx.x;
    int r = t >> 3, cg = (t & 7) * 4;
    if (n0 + cg + 3 < HW) {
        float4 v = *(const float4*)(x + (size_t)(b * INC + c0 + r) * HW + n0 + cg);
        tile[r][cg + 0] = v.x; tile[r][cg + 1] = v.y;
        tile[r][cg + 2] = v.z; tile[r][cg + 3] = v.w;
    }
    __syncthreads();
    int rn = t >> 3, cg2 = (t & 7) * 4;
    int n = n0 + rn;
    if (n < HW) {
        h4s h = { (f16)tile[cg2 + 0][rn], (f16)tile[cg2 + 1][rn],
                  (f16)tile[cg2 + 2][rn], (f16)tile[cg2 + 3][rn] };
        *(h4s*)(xh + ((size_t)b * HW + n) * INC + c0 + cg2) = h;
    }
}

// ---------------- GEMM1: sig_t[R][m] = stanh(Wq·xt[R] + u[R/784][m]) -------
__global__ __launch_bounds__(256) void gemm1_mfma(
    const f16* __restrict__ A,   // Wq [256][1024]
    const f16* __restrict__ B,   // xt [25088][1024]
    const float* __restrict__ u,
    f16* __restrict__ S) {       // sig [25088][256]
    const int R0 = blockIdx.x * 64;
    const int M0 = blockIdx.y * 128;
    __shared__ f16 Asm[128][40];
    __shared__ f16 Bsm[64][40];
    const int t = threadIdx.x;
    const int lane = t & 63, w = t >> 6;
    const int wc = (w >> 1) * 64;
    const int wr = (w & 1) * 32;
    const int ln = lane & 15, kg = lane >> 4;

    const int ar0 = t >> 2, ar1 = ar0 + 64;
    const int akc = (t & 3) * 8;
    const size_t aoff0 = (size_t)(M0 + ar0) * INC + akc;
    const size_t aoff1 = (size_t)(M0 + ar1) * INC + akc;
    const size_t boff  = (size_t)(R0 + ar0) * INC + akc;

    f4 acc[4][2];
    const f4 zero = {0.f, 0.f, 0.f, 0.f};
    #pragma unroll
    for (int i = 0; i < 4; ++i) { acc[i][0] = zero; acc[i][1] = zero; }

    hfrag rA0, rA1, rB;
    #define G1_LOAD(K0)                                   \
        rA0 = *(const hfrag*)(A + aoff0 + (K0));          \
        rA1 = *(const hfrag*)(A + aoff1 + (K0));          \
        rB  = *(const hfrag*)(B + boff  + (K0));

    G1_LOAD(0)
    for (int k0 = 0; k0 < INC; k0 += 32) {
        *(hfrag*)&Asm[ar0][akc] = rA0;
        *(hfrag*)&Asm[ar1][akc] = rA1;
        *(hfrag*)&Bsm[ar0][akc] = rB;
        __syncthreads();
        if (k0 + 32 < INC) { G1_LOAD(k0 + 32) }
        hfrag b0 = *(const hfrag*)&Bsm[wr + ln][kg * 8];
        hfrag b1 = *(const hfrag*)&Bsm[wr + 16 + ln][kg * 8];
        #pragma unroll
        for (int mi = 0; mi < 4; ++mi) {
            hfrag a = *(const hfrag*)&Asm[wc + mi * 16 + ln][kg * 8];
            acc[mi][0] = __builtin_amdgcn_mfma_f32_16x16x32_f16(a, b0, acc[mi][0], 0, 0, 0);
            acc[mi][1] = __builtin_amdgcn_mfma_f32_16x16x32_f16(a, b1, acc[mi][1], 0, 0, 0);
        }
        __syncthreads();
    }
    #undef G1_LOAD

    #pragma unroll
    for (int ni = 0; ni < 2; ++ni) {
        int R = R0 + wr + ni * 16 + ln;
        int b = R / HW;
        #pragma unroll
        for (int mi = 0; mi < 4; ++mi) {
            int mb = M0 + wc + mi * 16 + kg * 4;
            float uv[4];
            *(float4*)uv = *(const float4*)(u + b * MIDC + mb);
            h4s hv;
            hv.x = (f16)stanh_fast(acc[mi][ni][0] + uv[0]);
            hv.y = (f16)stanh_fast(acc[mi][ni][1] + uv[1]);
            hv.z = (f16)stanh_fast(acc[mi][ni][2] + uv[2]);
            hv.w = (f16)stanh_fast(acc[mi][ni][3] + uv[3]);
            *(h4s*)(S + (size_t)R * MIDC + mb) = hv;
        }
    }
}

// ---------------- GEMM2: alpha[b][c][n] = Ww·sig_t[R] + wb, R=(b,n) --------
__global__ __launch_bounds__(256) void gemm2_mfma(
    const f16* __restrict__ A,   // Ww [1024][256]
    const f16* __restrict__ B,   // sig [25088][256]
    const float* __restrict__ wb,
    float* __restrict__ aout) {
    const int R0 = blockIdx.x * 128;
    const int C0 = blockIdx.y * 128;
    __shared__ f16 Asm[128][40];
    __shared__ f16 Bsm[128][40];
    const int t = threadIdx.x;
    const int lane = t & 63, w = t >> 6;
    const int wc = (w >> 1) * 64;
    const int wr = (w & 1) * 64;
    const int ln = lane & 15, kg = lane >> 4;

    const int r0 = t >> 2, r1 = r0 + 64;
    const int kc = (t & 3) * 8;
    const size_t aoff0 = (size_t)(C0 + r0) * MIDC + kc;
    const size_t aoff1 = (size_t)(C0 + r1) * MIDC + kc;
    const size_t boff0 = (size_t)(R0 + r0) * MIDC + kc;
    const size_t boff1 = (size_t)(R0 + r1) * MIDC + kc;

    f4 acc[4][4];
    const f4 zero = {0.f, 0.f, 0.f, 0.f};
    #pragma unroll
    for (int i = 0; i < 4; ++i)
        #pragma unroll
        for (int j = 0; j < 4; ++j) acc[i][j] = zero;

    hfrag rA0, rA1, rB0, rB1;
    #define G2_LOAD(K0)                                   \
        rA0 = *(const hfrag*)(A + aoff0 + (K0));          \
        rA1 = *(const hfrag*)(A + aoff1 + (K0));          \
        rB0 = *(const hfrag*)(B + boff0 + (K0));          \
        rB1 = *(const hfrag*)(B + boff1 + (K0));

    G2_LOAD(0)
    for (int k0 = 0; k0 < MIDC; k0 += 32) {
        *(hfrag*)&Asm[r0][kc] = rA0;
        *(hfrag*)&Asm[r1][kc] = rA1;
        *(hfrag*)&Bsm[r0][kc] = rB0;
        *(hfrag*)&Bsm[r1][kc] = rB1;
        __syncthreads();
        if (k0 + 32 < MIDC) { G2_LOAD(k0 + 32) }
        hfrag bh[4];
        #pragma unroll
        for (int ni = 0; ni < 4; ++ni)
            bh[ni] = *(const hfrag*)&Bsm[wr + ni * 16 + ln][kg * 8];
        #pragma unroll
        for (int mi = 0; mi < 4; ++mi) {
            hfrag a = *(const hfrag*)&Asm[wc + mi * 16 + ln][kg * 8];
            #pragma unroll
            for (int ni = 0; ni < 4; ++ni)
                acc[mi][ni] = __builtin_amdgcn_mfma_f32_16x16x32_f16(a, bh[ni], acc[mi][ni], 0, 0, 0);
        }
        __syncthreads();
    }
    #undef G2_LOAD

    #pragma unroll
    for (int ni = 0; ni < 4; ++ni) {
        int R = R0 + wr + ni * 16 + ln;
        int b = R / HW;
        int n = R - b * HW;
        float* arow = aout + (size_t)b * INC * HW + n;
        #pragma unroll
        for (int mi = 0; mi < 4; ++mi) {
            int cb = C0 + wc + mi * 16 + kg * 4;
            float wv[4];
            *(float4*)wv = *(const float4*)(wb + cb);
            #pragma unroll
            for (int r = 0; r < 4; ++r)
                arow[(size_t)(cb + r) * HW] = acc[mi][ni][r] + wv[r];
        }
    }
}

// ---------------- per-(b,c) row: radix-select v5 ----------------------------
// v3 algorithm + (a) 8 sub-histograms, stride 260 (260 mod 32 = 4 -> all 8 on
// distinct banks; halves hot-bin atomic depth vs 4 subgroups), (b) -INF pads
// (key 0x007FFFFF, below all finite reals) with COMPILE-TIME slot predication
// (slots 0..11 always real; 12..15 gated by has3), (c) unpredicated max
// (pads mask to 0 like real masked values), (d) unpredicated exp-sum with
// closed-form pad correction: 60 lanes x 4 pads contribute 240*e^(-mx).
__global__ __launch_bounds__(256) void topk_softmax_reduce(const float* __restrict__ x,
                                                           float* __restrict__ out) {
    const int wid  = threadIdx.x >> 6;
    const int lane = threadIdx.x & 63;
    const int row  = blockIdx.x * 4 + wid;
    float* arow = out + BATCH * INC + (size_t)row * HW;
    const float* xrow = x + (size_t)row * HW;

    __shared__ int hist[4][8][260];   // [wave][subgroup][bin(+pad)] = 33.3 KB
    int* hp0 = &hist[wid][0][0];
    const int g = lane >> 3;          // 8-lane subgroup

    const bool has3 = (lane < 4);
    float4 v4[4];
    uint32_t key[16];

    {   // vectorized load of the row (196 float4 chunks)
        const float4* ap = (const float4*)arow;
        v4[0] = ap[lane];
        v4[1] = ap[lane + 64];
        v4[2] = ap[lane + 128];
        v4[3] = has3 ? ap[192 + lane]
                     : make_float4(-INFINITY, -INFINITY, -INFINITY, -INFINITY);
    }
    const float* vv = (const float*)v4;
    #pragma unroll
    for (int i = 0; i < 16; ++i) {
        uint32_t uu = __float_as_uint(vv[i]);
        key[i] = (uu & 0x80000000u) ? ~uu : (uu | 0x80000000u);
    }

    int kk = KSEL;
    uint32_t prefix = 0;
    uint32_t thkey = 0;
    bool done = false;

    #pragma unroll
    for (int round = 0; round < 4; ++round) {
        if (!done) {
            const int shift = 24 - 8 * round;
            const int4 z4 = {0, 0, 0, 0};
            if (round == 0) {
                int4* hz = (int4*)hp0;
                #pragma unroll
                for (int j = 0; j < 9; ++j) {       // zero 8*260 = 520 int4
                    int idx = lane + 64 * j;
                    if (idx < 520) hz[idx] = z4;
                }
                #pragma unroll
                for (int i = 0; i < 12; ++i)
                    atomicAdd(&hist[wid][g][key[i] >> 24], 1);
                if (has3) {
                    #pragma unroll
                    for (int i = 12; i < 16; ++i)
                        atomicAdd(&hist[wid][g][key[i] >> 24], 1);
                }
            } else {
                ((int4*)hp0)[lane] = z4;            // zero bins 0..255
                const uint32_t himask = 0xFFFFFFFFu << (shift + 8);
                #pragma unroll
                for (int i = 0; i < 16; ++i)
                    if ((i < 12 || has3) && (key[i] & himask) == prefix)
                        atomicAdd(&hp0[(key[i] >> shift) & 255], 1);
            }

            int h0, h1, h2, h3;
            if (round == 0) {
                h0 = 0; h1 = 0; h2 = 0; h3 = 0;
                #pragma unroll
                for (int sgi = 0; sgi < 8; ++sgi) {
                    int4 c = *(const int4*)&hist[wid][sgi][4 * lane];
                    h0 += c.x; h1 += c.y; h2 += c.z; h3 += c.w;
                }
            } else {
                int4 c = *(const int4*)&hp0[4 * lane];
                h0 = c.x; h1 = c.y; h2 = c.z; h3 = c.w;
            }
            int gsum = h0 + h1 + h2 + h3;
            int suf = gsum;
            #pragma unroll
            for (int off = 1; off < 64; off <<= 1) {
                int o = __shfl_down(suf, off, 64);
                suf += (lane + off < 64) ? o : 0;
            }
            int ex = suf - gsum;
            int cgt3 = ex, cgt2 = cgt3 + h3, cgt1 = cgt2 + h2, cgt0 = cgt1 + h1;
            int bsel = -1, cg = 0, hs = 0;
            if (cgt0 < kk && kk <= cgt0 + h0) { bsel = 4 * lane + 0; cg = cgt0; hs = h0; }
            if (cgt1 < kk && kk <= cgt1 + h1) { bsel = 4 * lane + 1; cg = cgt1; hs = h1; }
            if (cgt2 < kk && kk <= cgt2 + h2) { bsel = 4 * lane + 2; cg = cgt2; hs = h2; }
            if (cgt3 < kk && kk <= cgt3 + h3) { bsel = 4 * lane + 3; cg = cgt3; hs = h3; }
            unsigned long long m = __ballot(bsel >= 0);
            int src = (int)__ffsll((long long)m) - 1;
            bsel = __shfl(bsel, src, 64);
            cg   = __shfl(cg,   src, 64);
            hs   = __shfl(hs,   src, 64);
            kk -= cg;
            prefix |= ((uint32_t)bsel) << shift;

            if (shift == 0) {
                thkey = prefix;
                done = true;
            } else if (kk == 1 || kk == hs) {
                const uint32_t maskP = 0xFFFFFFFFu << shift;
                bool want_max = (kk == 1);
                uint32_t r = want_max ? 0u : 0xFFFFFFFFu;
                #pragma unroll
                for (int i = 0; i < 16; ++i) {
                    if ((i < 12 || has3) && (key[i] & maskP) == prefix)
                        r = want_max ? (r > key[i] ? r : key[i])
                                     : (r < key[i] ? r : key[i]);
                }
                #pragma unroll
                for (int off = 32; off; off >>= 1) {
                    uint32_t o = __shfl_xor(r, off, 64);
                    r = want_max ? (r > o ? r : o) : (r < o ? r : o);
                }
                thkey = r;
                done = true;
            }
        }
    }

    uint32_t tu = (thkey & 0x80000000u) ? (thkey ^ 0x80000000u) : ~thkey;
    const float th = __uint_as_float(tu);

    // mask + max (pads: -INF < th -> 0, same as real masked values)
    float* vw = (float*)v4;
    float mx = -INFINITY;
    #pragma unroll
    for (int i = 0; i < 16; ++i) {
        float f = vw[i];
        f = (f < th) ? 0.0f : f;
        vw[i] = f;
        mx = fmaxf(mx, f);
    }
    #pragma unroll
    for (int off = 32; off; off >>= 1) mx = fmaxf(mx, __shfl_xor(mx, off, 64));

    // exp + sum (unpredicated; subtract 240 pad contributions of e^{-mx})
    float sum = 0.f;
    #pragma unroll
    for (int i = 0; i < 16; ++i) {
        float e = __expf(vw[i] - mx);
        vw[i] = e;
        sum += e;
    }
    #pragma unroll
    for (int off = 32; off; off >>= 1) sum += __shfl_xor(sum, off, 64);
    sum -= 240.0f * __expf(0.0f - mx);
    float inv = 1.0f / sum;

    // normalize + store atten + weighted reduce against x
    float dot = 0.f;
    {
        float4* ap = (float4*)arow;
        const float4* xp = (const float4*)xrow;
        #pragma unroll
        for (int ci = 0; ci < 4; ++ci) {
            if (ci == 3 && !has3) break;
            int chunk = (ci < 3) ? (lane + 64 * ci) : (192 + lane);
            float4 a;
            a.x = vw[ci * 4 + 0] * inv;
            a.y = vw[ci * 4 + 1] * inv;
            a.z = vw[ci * 4 + 2] * inv;
            a.w = vw[ci * 4 + 3] * inv;
            ap[chunk] = a;
            float4 xl = xp[chunk];
            dot += xl.x * a.x + xl.y * a.y + xl.z * a.z + xl.w * a.w;
        }
    }
    #pragma unroll
    for (int off = 32; off; off >>= 1) dot += __shfl_xor(dot, off, 64);
    if (lane == 0) out[row] = dot;
}

extern "C" void kernel_launch(void* const* d_in, const int* in_sizes, int n_in,
                              void* d_out, int out_size, void* d_ws, size_t ws_size,
                              hipStream_t stream) {
    const float* x    = (const float*)d_in[0];
    const float* s    = (const float*)d_in[1];
    const float* Wq_w = (const float*)d_in[2];
    const float* Wq_b = (const float*)d_in[3];
    const float* Uq_w = (const float*)d_in[4];
    const float* w_w  = (const float*)d_in[5];
    const float* w_b  = (const float*)d_in[6];
    float* out = (float*)d_out;

    f16* xt   = (f16*)d_ws;                                   // [25088][1024]
    f16* sig  = xt + (size_t)ROWS * INC;                      // [25088][256]
    f16* wq_h = sig + (size_t)ROWS * MIDC;                    // [256][1024]
    f16* ww_h = wq_h + MIDC * INC;                            // [1024][256]
    float* u  = (float*)(ww_h + INC * MIDC);                  // [32][256]
    float* alpha = out + BATCH * INC;                         // staged in atten slot

    prologue<<<544, 256, 0, stream>>>(Wq_w, w_w, s, Uq_w, Wq_b, wq_h, ww_h, u);
    prep_x<<<dim3(25, 32, 32), 256, 0, stream>>>(x, xt);
    gemm1_mfma<<<dim3(ROWS / 64, 2), 256, 0, stream>>>(wq_h, xt, u, sig);
    gemm2_mfma<<<dim3(ROWS / 128, 8), 256, 0, stream>>>(ww_h, sig, w_b, alpha);
    topk_softmax_reduce<<<BATCH * INC / 4, 256, 0, stream>>>(x, out);
}

// Round 11
// 169.822 us; speedup vs baseline: 1.5367x; 1.0458x over previous
//
#include <hip/hip_runtime.h>
#include <hip/hip_bf16.h>
#include <hip/hip_fp16.h>
#include <math.h>

#define BATCH 32
#define INC 1024
#define MIDC 256
#define SC 256
#define HW 784
#define ROWS 25088   // BATCH*HW
#define KSEL 196     // int(0.25 * 784)

typedef _Float16 f16;
typedef __attribute__((ext_vector_type(8))) _Float16 hfrag;  // 8 fp16 (4 VGPRs)
typedef __attribute__((ext_vector_type(4))) float f4;        // 4 fp32 acc

struct alignas(8) h4s { f16 x, y, z, w; };

__device__ inline float stanh_fast(float p) {
    // 1.7159*tanh(2p/3) = 1.7159*(1 - 2/(exp(4p/3)+1))
    float e = __expf(1.33333333f * p);
    return 1.7159f * (1.0f - 2.0f / (e + 1.0f));
}

// ---------------- prep_all: x-transpose + weight cvt + calc_u, one launch --
// blocks [0,25600): prep_x; [25600,25856): cvt Wq; [25856,26112): cvt Ww;
// [26112,26144): calc_u.
__global__ __launch_bounds__(256) void prep_all(
    const float* __restrict__ x,
    const float* __restrict__ Wq_w, const float* __restrict__ w_w,
    const float* __restrict__ s, const float* __restrict__ Uq_w,
    const float* __restrict__ Wq_b,
    f16* __restrict__ xh, f16* __restrict__ wq_h, f16* __restrict__ ww_h,
    float* __restrict__ u) {
    __shared__ float tile[32][33];
    const int bid = blockIdx.x;
    const int t = threadIdx.x;
    if (bid < 25600) {                     // ---- prep_x ----
        int b = bid / 800, rem = bid - b * 800;
        int c0 = (rem / 25) * 32, n0 = (rem % 25) * 32;
        int r = t >> 3, cg = (t & 7) * 4;
        if (n0 + cg + 3 < HW) {
            float4 v = *(const float4*)(x + (size_t)(b * INC + c0 + r) * HW + n0 + cg);
            tile[r][cg + 0] = v.x; tile[r][cg + 1] = v.y;
            tile[r][cg + 2] = v.z; tile[r][cg + 3] = v.w;
        }
        __syncthreads();
        int rn = t >> 3, cg2 = (t & 7) * 4;
        int n = n0 + rn;
        if (n < HW) {
            h4s h = { (f16)tile[cg2 + 0][rn], (f16)tile[cg2 + 1][rn],
                      (f16)tile[cg2 + 2][rn], (f16)tile[cg2 + 3][rn] };
            *(h4s*)(xh + ((size_t)b * HW + n) * INC + c0 + cg2) = h;
        }
    } else if (bid < 25856) {              // ---- cvt Wq ----
        int i = (bid - 25600) * 256 + t;
        float4 v = ((const float4*)Wq_w)[i];
        h4s h = { (f16)v.x, (f16)v.y, (f16)v.z, (f16)v.w };
        ((h4s*)wq_h)[i] = h;
    } else if (bid < 26112) {              // ---- cvt Ww ----
        int i = (bid - 25856) * 256 + t;
        float4 v = ((const float4*)w_w)[i];
        h4s h = { (f16)v.x, (f16)v.y, (f16)v.z, (f16)v.w };
        ((h4s*)ww_h)[i] = h;
    } else {                               // ---- calc_u ----
        int b = bid - 26112;
        float* ssh = &tile[0][0];
        ssh[t] = s[b * SC + t];
        __syncthreads();
        float acc = Wq_b[t];
        const float* uq = Uq_w + (size_t)t * SC;
        #pragma unroll 8
        for (int i = 0; i < SC; ++i) acc += ssh[i] * uq[i];
        u[b * MIDC + t] = acc;
    }
}

// ---------------- GEMM1: sig_t[R][m] = stanh(Wq·xt[R] + u[R/784][m]) -------
__global__ __launch_bounds__(256) void gemm1_mfma(
    const f16* __restrict__ A,   // Wq [256][1024]
    const f16* __restrict__ B,   // xt [25088][1024]
    const float* __restrict__ u,
    f16* __restrict__ S) {       // sig [25088][256]
    const int R0 = blockIdx.x * 64;
    const int M0 = blockIdx.y * 128;
    __shared__ f16 Asm[128][40];
    __shared__ f16 Bsm[64][40];
    const int t = threadIdx.x;
    const int lane = t & 63, w = t >> 6;
    const int wc = (w >> 1) * 64;
    const int wr = (w & 1) * 32;
    const int ln = lane & 15, kg = lane >> 4;

    const int ar0 = t >> 2, ar1 = ar0 + 64;
    const int akc = (t & 3) * 8;
    const size_t aoff0 = (size_t)(M0 + ar0) * INC + akc;
    const size_t aoff1 = (size_t)(M0 + ar1) * INC + akc;
    const size_t boff  = (size_t)(R0 + ar0) * INC + akc;

    f4 acc[4][2];
    const f4 zero = {0.f, 0.f, 0.f, 0.f};
    #pragma unroll
    for (int i = 0; i < 4; ++i) { acc[i][0] = zero; acc[i][1] = zero; }

    hfrag rA0, rA1, rB;
    #define G1_LOAD(K0)                                   \
        rA0 = *(const hfrag*)(A + aoff0 + (K0));          \
        rA1 = *(const hfrag*)(A + aoff1 + (K0));          \
        rB  = *(const hfrag*)(B + boff  + (K0));

    G1_LOAD(0)
    for (int k0 = 0; k0 < INC; k0 += 32) {
        *(hfrag*)&Asm[ar0][akc] = rA0;
        *(hfrag*)&Asm[ar1][akc] = rA1;
        *(hfrag*)&Bsm[ar0][akc] = rB;
        __syncthreads();
        if (k0 + 32 < INC) { G1_LOAD(k0 + 32) }
        hfrag b0 = *(const hfrag*)&Bsm[wr + ln][kg * 8];
        hfrag b1 = *(const hfrag*)&Bsm[wr + 16 + ln][kg * 8];
        #pragma unroll
        for (int mi = 0; mi < 4; ++mi) {
            hfrag a = *(const hfrag*)&Asm[wc + mi * 16 + ln][kg * 8];
            acc[mi][0] = __builtin_amdgcn_mfma_f32_16x16x32_f16(a, b0, acc[mi][0], 0, 0, 0);
            acc[mi][1] = __builtin_amdgcn_mfma_f32_16x16x32_f16(a, b1, acc[mi][1], 0, 0, 0);
        }
        __syncthreads();
    }
    #undef G1_LOAD

    #pragma unroll
    for (int ni = 0; ni < 2; ++ni) {
        int R = R0 + wr + ni * 16 + ln;
        int b = R / HW;
        #pragma unroll
        for (int mi = 0; mi < 4; ++mi) {
            int mb = M0 + wc + mi * 16 + kg * 4;
            float uv[4];
            *(float4*)uv = *(const float4*)(u + b * MIDC + mb);
            h4s hv;
            hv.x = (f16)stanh_fast(acc[mi][ni][0] + uv[0]);
            hv.y = (f16)stanh_fast(acc[mi][ni][1] + uv[1]);
            hv.z = (f16)stanh_fast(acc[mi][ni][2] + uv[2]);
            hv.w = (f16)stanh_fast(acc[mi][ni][3] + uv[3]);
            *(h4s*)(S + (size_t)R * MIDC + mb) = hv;
        }
    }
}

// ---------------- GEMM2: alpha[b][c][n] = Ww·sig_t[R] + wb, R=(b,n) --------
__global__ __launch_bounds__(256) void gemm2_mfma(
    const f16* __restrict__ A,   // Ww [1024][256]
    const f16* __restrict__ B,   // sig [25088][256]
    const float* __restrict__ wb,
    float* __restrict__ aout) {
    const int R0 = blockIdx.x * 128;
    const int C0 = blockIdx.y * 128;
    __shared__ f16 Asm[128][40];
    __shared__ f16 Bsm[128][40];
    const int t = threadIdx.x;
    const int lane = t & 63, w = t >> 6;
    const int wc = (w >> 1) * 64;
    const int wr = (w & 1) * 64;
    const int ln = lane & 15, kg = lane >> 4;

    const int r0 = t >> 2, r1 = r0 + 64;
    const int kc = (t & 3) * 8;
    const size_t aoff0 = (size_t)(C0 + r0) * MIDC + kc;
    const size_t aoff1 = (size_t)(C0 + r1) * MIDC + kc;
    const size_t boff0 = (size_t)(R0 + r0) * MIDC + kc;
    const size_t boff1 = (size_t)(R0 + r1) * MIDC + kc;

    f4 acc[4][4];
    const f4 zero = {0.f, 0.f, 0.f, 0.f};
    #pragma unroll
    for (int i = 0; i < 4; ++i)
        #pragma unroll
        for (int j = 0; j < 4; ++j) acc[i][j] = zero;

    hfrag rA0, rA1, rB0, rB1;
    #define G2_LOAD(K0)                                   \
        rA0 = *(const hfrag*)(A + aoff0 + (K0));          \
        rA1 = *(const hfrag*)(A + aoff1 + (K0));          \
        rB0 = *(const hfrag*)(B + boff0 + (K0));          \
        rB1 = *(const hfrag*)(B + boff1 + (K0));

    G2_LOAD(0)
    for (int k0 = 0; k0 < MIDC; k0 += 32) {
        *(hfrag*)&Asm[r0][kc] = rA0;
        *(hfrag*)&Asm[r1][kc] = rA1;
        *(hfrag*)&Bsm[r0][kc] = rB0;
        *(hfrag*)&Bsm[r1][kc] = rB1;
        __syncthreads();
        if (k0 + 32 < MIDC) { G2_LOAD(k0 + 32) }
        hfrag bh[4];
        #pragma unroll
        for (int ni = 0; ni < 4; ++ni)
            bh[ni] = *(const hfrag*)&Bsm[wr + ni * 16 + ln][kg * 8];
        #pragma unroll
        for (int mi = 0; mi < 4; ++mi) {
            hfrag a = *(const hfrag*)&Asm[wc + mi * 16 + ln][kg * 8];
            #pragma unroll
            for (int ni = 0; ni < 4; ++ni)
                acc[mi][ni] = __builtin_amdgcn_mfma_f32_16x16x32_f16(a, bh[ni], acc[mi][ni], 0, 0, 0);
        }
        __syncthreads();
    }
    #undef G2_LOAD

    #pragma unroll
    for (int ni = 0; ni < 4; ++ni) {
        int R = R0 + wr + ni * 16 + ln;
        int b = R / HW;
        int n = R - b * HW;
        float* arow = aout + (size_t)b * INC * HW + n;
        #pragma unroll
        for (int mi = 0; mi < 4; ++mi) {
            int cb = C0 + wc + mi * 16 + kg * 4;
            float wv[4];
            *(float4*)wv = *(const float4*)(wb + cb);
            #pragma unroll
            for (int r = 0; r < 4; ++r)
                arow[(size_t)(cb + r) * HW] = acc[mi][ni][r] + wv[r];
        }
    }
}

// ---------------- per-(b,c) row: radix-select v6 ----------------------------
// R6's v3 structure (4 sub-histograms, 264-int stride, 16.9 KB LDS — best
// measured) + R10's VALU shaves: -INF pads (key 0x007FFFFF, below all finite
// reals) with COMPILE-TIME slot predication (slots 0..11 always real, 12..15
// gated by has3), unpredicated mask+max (pads behave like masked zeros), and
// unpredicated exp-sum with closed-form pad correction (240 pads * e^{-mx}).
__global__ __launch_bounds__(256) void topk_softmax_reduce(const float* __restrict__ x,
                                                           float* __restrict__ out) {
    const int wid  = threadIdx.x >> 6;
    const int lane = threadIdx.x & 63;
    const int row  = blockIdx.x * 4 + wid;
    float* arow = out + BATCH * INC + (size_t)row * HW;
    const float* xrow = x + (size_t)row * HW;

    __shared__ int hist[4][4][264];   // [wave][subgroup][bin(+pad)] = 16.9 KB
    int* hp0 = &hist[wid][0][0];
    const int g = lane >> 4;          // quarter-wave subgroup

    const bool has3 = (lane < 4);
    float4 v4[4];
    uint32_t key[16];

    {   // vectorized load of the row (196 float4 chunks)
        const float4* ap = (const float4*)arow;
        v4[0] = ap[lane];
        v4[1] = ap[lane + 64];
        v4[2] = ap[lane + 128];
        v4[3] = has3 ? ap[192 + lane]
                     : make_float4(-INFINITY, -INFINITY, -INFINITY, -INFINITY);
    }
    const float* vv = (const float*)v4;
    #pragma unroll
    for (int i = 0; i < 16; ++i) {
        uint32_t uu = __float_as_uint(vv[i]);
        key[i] = (uu & 0x80000000u) ? ~uu : (uu | 0x80000000u);
    }

    int kk = KSEL;
    uint32_t prefix = 0;
    uint32_t thkey = 0;
    bool done = false;

    #pragma unroll
    for (int round = 0; round < 4; ++round) {
        if (!done) {
            const int shift = 24 - 8 * round;
            const int4 z4 = {0, 0, 0, 0};
            if (round == 0) {
                #pragma unroll
                for (int j = 0; j < 5; ++j) {
                    int idx = lane + 64 * j;
                    if (idx < 264) ((int4*)hp0)[idx] = z4;   // zero all 4*264 ints
                }
                #pragma unroll
                for (int i = 0; i < 12; ++i)
                    atomicAdd(&hist[wid][g][key[i] >> 24], 1);
                if (has3) {
                    #pragma unroll
                    for (int i = 12; i < 16; ++i)
                        atomicAdd(&hist[wid][g][key[i] >> 24], 1);
                }
            } else {
                ((int4*)hp0)[lane] = z4;      // zero bins 0..255
                const uint32_t himask = 0xFFFFFFFFu << (shift + 8);
                #pragma unroll
                for (int i = 0; i < 16; ++i)
                    if ((i < 12 || has3) && (key[i] & himask) == prefix)
                        atomicAdd(&hp0[(key[i] >> shift) & 255], 1);
            }

            int h0, h1, h2, h3;
            if (round == 0) {
                int4 c0 = *(const int4*)&hist[wid][0][4 * lane];
                int4 c1 = *(const int4*)&hist[wid][1][4 * lane];
                int4 c2 = *(const int4*)&hist[wid][2][4 * lane];
                int4 c3 = *(const int4*)&hist[wid][3][4 * lane];
                h0 = c0.x + c1.x + c2.x + c3.x;
                h1 = c0.y + c1.y + c2.y + c3.y;
                h2 = c0.z + c1.z + c2.z + c3.z;
                h3 = c0.w + c1.w + c2.w + c3.w;
            } else {
                int4 c = *(const int4*)&hp0[4 * lane];
                h0 = c.x; h1 = c.y; h2 = c.z; h3 = c.w;
            }
            int gsum = h0 + h1 + h2 + h3;
            int suf = gsum;
            #pragma unroll
            for (int off = 1; off < 64; off <<= 1) {
                int o = __shfl_down(suf, off, 64);
                suf += (lane + off < 64) ? o : 0;
            }
            int ex = suf - gsum;
            int cgt3 = ex, cgt2 = cgt3 + h3, cgt1 = cgt2 + h2, cgt0 = cgt1 + h1;
            int bsel = -1, cg = 0, hs = 0;
            if (cgt0 < kk && kk <= cgt0 + h0) { bsel = 4 * lane + 0; cg = cgt0; hs = h0; }
            if (cgt1 < kk && kk <= cgt1 + h1) { bsel = 4 * lane + 1; cg = cgt1; hs = h1; }
            if (cgt2 < kk && kk <= cgt2 + h2) { bsel = 4 * lane + 2; cg = cgt2; hs = h2; }
            if (cgt3 < kk && kk <= cgt3 + h3) { bsel = 4 * lane + 3; cg = cgt3; hs = h3; }
            unsigned long long m = __ballot(bsel >= 0);
            int src = (int)__ffsll((long long)m) - 1;
            bsel = __shfl(bsel, src, 64);
            cg   = __shfl(cg,   src, 64);
            hs   = __shfl(hs,   src, 64);
            kk -= cg;
            prefix |= ((uint32_t)bsel) << shift;

            if (shift == 0) {
                thkey = prefix;
                done = true;
            } else if (kk == 1 || kk == hs) {
                const uint32_t maskP = 0xFFFFFFFFu << shift;
                bool want_max = (kk == 1);
                uint32_t r = want_max ? 0u : 0xFFFFFFFFu;
                #pragma unroll
                for (int i = 0; i < 16; ++i) {
                    if ((i < 12 || has3) && (key[i] & maskP) == prefix)
                        r = want_max ? (r > key[i] ? r : key[i])
                                     : (r < key[i] ? r : key[i]);
                }
                #pragma unroll
                for (int off = 32; off; off >>= 1) {
                    uint32_t o = __shfl_xor(r, off, 64);
                    r = want_max ? (r > o ? r : o) : (r < o ? r : o);
                }
                thkey = r;
                done = true;
            }
        }
    }

    uint32_t tu = (thkey & 0x80000000u) ? (thkey ^ 0x80000000u) : ~thkey;
    const float th = __uint_as_float(tu);

    // mask + max (pads: -INF < th -> 0, exactly like real masked values)
    float* vw = (float*)v4;
    float mx = -INFINITY;
    #pragma unroll
    for (int i = 0; i < 16; ++i) {
        float f = vw[i];
        f = (f < th) ? 0.0f : f;
        vw[i] = f;
        mx = fmaxf(mx, f);
    }
    #pragma unroll
    for (int off = 32; off; off >>= 1) mx = fmaxf(mx, __shfl_xor(mx, off, 64));

    // exp + sum (unpredicated; subtract the 240 pad contributions of e^{-mx})
    float sum = 0.f;
    #pragma unroll
    for (int i = 0; i < 16; ++i) {
        float e = __expf(vw[i] - mx);
        vw[i] = e;
        sum += e;
    }
    #pragma unroll
    for (int off = 32; off; off >>= 1) sum += __shfl_xor(sum, off, 64);
    sum -= 240.0f * __expf(0.0f - mx);
    float inv = 1.0f / sum;

    // normalize + store atten + weighted reduce against x
    float dot = 0.f;
    {
        float4* ap = (float4*)arow;
        const float4* xp = (const float4*)xrow;
        #pragma unroll
        for (int ci = 0; ci < 4; ++ci) {
            if (ci == 3 && !has3) break;
            int chunk = (ci < 3) ? (lane + 64 * ci) : (192 + lane);
            float4 a;
            a.x = vw[ci * 4 + 0] * inv;
            a.y = vw[ci * 4 + 1] * inv;
            a.z = vw[ci * 4 + 2] * inv;
            a.w = vw[ci * 4 + 3] * inv;
            ap[chunk] = a;
            float4 xl = xp[chunk];
            dot += xl.x * a.x + xl.y * a.y + xl.z * a.z + xl.w * a.w;
        }
    }
    #pragma unroll
    for (int off = 32; off; off >>= 1) dot += __shfl_xor(dot, off, 64);
    if (lane == 0) out[row] = dot;
}

extern "C" void kernel_launch(void* const* d_in, const int* in_sizes, int n_in,
                              void* d_out, int out_size, void* d_ws, size_t ws_size,
                              hipStream_t stream) {
    const float* x    = (const float*)d_in[0];
    const float* s    = (const float*)d_in[1];
    const float* Wq_w = (const float*)d_in[2];
    const float* Wq_b = (const float*)d_in[3];
    const float* Uq_w = (const float*)d_in[4];
    const float* w_w  = (const float*)d_in[5];
    const float* w_b  = (const float*)d_in[6];
    float* out = (float*)d_out;

    f16* xt   = (f16*)d_ws;                                   // [25088][1024]
    f16* sig  = xt + (size_t)ROWS * INC;                      // [25088][256]
    f16* wq_h = sig + (size_t)ROWS * MIDC;                    // [256][1024]
    f16* ww_h = wq_h + MIDC * INC;                            // [1024][256]
    float* u  = (float*)(ww_h + INC * MIDC);                  // [32][256]
    float* alpha = out + BATCH * INC;                         // staged in atten slot

    prep_all<<<26144, 256, 0, stream>>>(x, Wq_w, w_w, s, Uq_w, Wq_b,
                                        xt, wq_h, ww_h, u);
    gemm1_mfma<<<dim3(ROWS / 64, 2), 256, 0, stream>>>(wq_h, xt, u, sig);
    gemm2_mfma<<<dim3(ROWS / 128, 8), 256, 0, stream>>>(ww_h, sig, w_b, alpha);
    topk_softmax_reduce<<<BATCH * INC / 4, 256, 0, stream>>>(x, out);
}

// Round 12
// 165.800 us; speedup vs baseline: 1.5740x; 1.0243x over previous
//
#include <hip/hip_runtime.h>
#include <hip/hip_bf16.h>
#include <hip/hip_fp16.h>
#include <math.h>

#define BATCH 32
#define INC 1024
#define MIDC 256
#define SC 256
#define HW 784
#define ROWS 25088   // BATCH*HW
#define KSEL 196     // int(0.25 * 784)

typedef _Float16 f16;
typedef __attribute__((ext_vector_type(8))) _Float16 hfrag;  // 8 fp16 (4 VGPRs)
typedef __attribute__((ext_vector_type(4))) float f4;        // 4 fp32 acc

struct alignas(8) h4s { f16 x, y, z, w; };

__device__ inline float stanh_fast(float p) {
    // 1.7159*tanh(2p/3) = 1.7159*(1 - 2/(exp(4p/3)+1))
    float e = __expf(1.33333333f * p);
    return 1.7159f * (1.0f - 2.0f / (e + 1.0f));
}

// ---------------- prep_all: x-transpose + weight cvt + calc_u, one launch --
// blocks [0,25600): prep_x; [25600,25856): cvt Wq; [25856,26112): cvt Ww;
// [26112,26144): calc_u.
__global__ __launch_bounds__(256) void prep_all(
    const float* __restrict__ x,
    const float* __restrict__ Wq_w, const float* __restrict__ w_w,
    const float* __restrict__ s, const float* __restrict__ Uq_w,
    const float* __restrict__ Wq_b,
    f16* __restrict__ xh, f16* __restrict__ wq_h, f16* __restrict__ ww_h,
    float* __restrict__ u) {
    __shared__ float tile[32][33];
    const int bid = blockIdx.x;
    const int t = threadIdx.x;
    if (bid < 25600) {                     // ---- prep_x ----
        int b = bid / 800, rem = bid - b * 800;
        int c0 = (rem / 25) * 32, n0 = (rem % 25) * 32;
        int r = t >> 3, cg = (t & 7) * 4;
        if (n0 + cg + 3 < HW) {
            float4 v = *(const float4*)(x + (size_t)(b * INC + c0 + r) * HW + n0 + cg);
            tile[r][cg + 0] = v.x; tile[r][cg + 1] = v.y;
            tile[r][cg + 2] = v.z; tile[r][cg + 3] = v.w;
        }
        __syncthreads();
        int rn = t >> 3, cg2 = (t & 7) * 4;
        int n = n0 + rn;
        if (n < HW) {
            h4s h = { (f16)tile[cg2 + 0][rn], (f16)tile[cg2 + 1][rn],
                      (f16)tile[cg2 + 2][rn], (f16)tile[cg2 + 3][rn] };
            *(h4s*)(xh + ((size_t)b * HW + n) * INC + c0 + cg2) = h;
        }
    } else if (bid < 25856) {              // ---- cvt Wq ----
        int i = (bid - 25600) * 256 + t;
        float4 v = ((const float4*)Wq_w)[i];
        h4s h = { (f16)v.x, (f16)v.y, (f16)v.z, (f16)v.w };
        ((h4s*)wq_h)[i] = h;
    } else if (bid < 26112) {              // ---- cvt Ww ----
        int i = (bid - 25856) * 256 + t;
        float4 v = ((const float4*)w_w)[i];
        h4s h = { (f16)v.x, (f16)v.y, (f16)v.z, (f16)v.w };
        ((h4s*)ww_h)[i] = h;
    } else {                               // ---- calc_u ----
        int b = bid - 26112;
        float* ssh = &tile[0][0];
        ssh[t] = s[b * SC + t];
        __syncthreads();
        float acc = Wq_b[t];
        const float* uq = Uq_w + (size_t)t * SC;
        #pragma unroll 8
        for (int i = 0; i < SC; ++i) acc += ssh[i] * uq[i];
        u[b * MIDC + t] = acc;
    }
}

// ---------------- GEMM1: sig_t[R][m] = stanh(Wq·xt[R] + u[R/784][m]) -------
// 128 rows x 128 mids per block (clone of the verified gemm2 body; strides
// MIDC->INC, K=1024, stanh+u epilogue). 8 MFMA->16 MFMA per K-step vs R11.
__global__ __launch_bounds__(256) void gemm1_mfma(
    const f16* __restrict__ A,   // Wq [256][1024]
    const f16* __restrict__ B,   // xt [25088][1024]
    const float* __restrict__ u,
    f16* __restrict__ S) {       // sig [25088][256]
    const int R0 = blockIdx.x * 128;
    const int M0 = blockIdx.y * 128;
    __shared__ f16 Asm[128][40];
    __shared__ f16 Bsm[128][40];
    const int t = threadIdx.x;
    const int lane = t & 63, w = t >> 6;
    const int wc = (w >> 1) * 64;      // mid offset within 128
    const int wr = (w & 1) * 64;       // row offset within 128
    const int ln = lane & 15, kg = lane >> 4;

    const int r0 = t >> 2, r1 = r0 + 64;
    const int kc = (t & 3) * 8;
    const size_t aoff0 = (size_t)(M0 + r0) * INC + kc;
    const size_t aoff1 = (size_t)(M0 + r1) * INC + kc;
    const size_t boff0 = (size_t)(R0 + r0) * INC + kc;
    const size_t boff1 = (size_t)(R0 + r1) * INC + kc;

    f4 acc[4][4];
    const f4 zero = {0.f, 0.f, 0.f, 0.f};
    #pragma unroll
    for (int i = 0; i < 4; ++i)
        #pragma unroll
        for (int j = 0; j < 4; ++j) acc[i][j] = zero;

    hfrag rA0, rA1, rB0, rB1;
    #define G1_LOAD(K0)                                   \
        rA0 = *(const hfrag*)(A + aoff0 + (K0));          \
        rA1 = *(const hfrag*)(A + aoff1 + (K0));          \
        rB0 = *(const hfrag*)(B + boff0 + (K0));          \
        rB1 = *(const hfrag*)(B + boff1 + (K0));

    G1_LOAD(0)
    for (int k0 = 0; k0 < INC; k0 += 32) {
        *(hfrag*)&Asm[r0][kc] = rA0;
        *(hfrag*)&Asm[r1][kc] = rA1;
        *(hfrag*)&Bsm[r0][kc] = rB0;
        *(hfrag*)&Bsm[r1][kc] = rB1;
        __syncthreads();
        if (k0 + 32 < INC) { G1_LOAD(k0 + 32) }
        hfrag bh[4];
        #pragma unroll
        for (int ni = 0; ni < 4; ++ni)
            bh[ni] = *(const hfrag*)&Bsm[wr + ni * 16 + ln][kg * 8];
        #pragma unroll
        for (int mi = 0; mi < 4; ++mi) {
            hfrag a = *(const hfrag*)&Asm[wc + mi * 16 + ln][kg * 8];
            #pragma unroll
            for (int ni = 0; ni < 4; ++ni)
                acc[mi][ni] = __builtin_amdgcn_mfma_f32_16x16x32_f16(a, bh[ni], acc[mi][ni], 0, 0, 0);
        }
        __syncthreads();
    }
    #undef G1_LOAD

    #pragma unroll
    for (int ni = 0; ni < 4; ++ni) {
        int R = R0 + wr + ni * 16 + ln;
        int b = R / HW;
        const float* ub = u + b * MIDC;
        #pragma unroll
        for (int mi = 0; mi < 4; ++mi) {
            int mb = M0 + wc + mi * 16 + kg * 4;
            float uv[4];
            *(float4*)uv = *(const float4*)(ub + mb);
            h4s hv;
            hv.x = (f16)stanh_fast(acc[mi][ni][0] + uv[0]);
            hv.y = (f16)stanh_fast(acc[mi][ni][1] + uv[1]);
            hv.z = (f16)stanh_fast(acc[mi][ni][2] + uv[2]);
            hv.w = (f16)stanh_fast(acc[mi][ni][3] + uv[3]);
            *(h4s*)(S + (size_t)R * MIDC + mb) = hv;
        }
    }
}

// ---------------- GEMM2: alpha[b][c][n] = Ww·sig_t[R] + wb, R=(b,n) --------
__global__ __launch_bounds__(256) void gemm2_mfma(
    const f16* __restrict__ A,   // Ww [1024][256]
    const f16* __restrict__ B,   // sig [25088][256]
    const float* __restrict__ wb,
    float* __restrict__ aout) {
    const int R0 = blockIdx.x * 128;
    const int C0 = blockIdx.y * 128;
    __shared__ f16 Asm[128][40];
    __shared__ f16 Bsm[128][40];
    const int t = threadIdx.x;
    const int lane = t & 63, w = t >> 6;
    const int wc = (w >> 1) * 64;
    const int wr = (w & 1) * 64;
    const int ln = lane & 15, kg = lane >> 4;

    const int r0 = t >> 2, r1 = r0 + 64;
    const int kc = (t & 3) * 8;
    const size_t aoff0 = (size_t)(C0 + r0) * MIDC + kc;
    const size_t aoff1 = (size_t)(C0 + r1) * MIDC + kc;
    const size_t boff0 = (size_t)(R0 + r0) * MIDC + kc;
    const size_t boff1 = (size_t)(R0 + r1) * MIDC + kc;

    f4 acc[4][4];
    const f4 zero = {0.f, 0.f, 0.f, 0.f};
    #pragma unroll
    for (int i = 0; i < 4; ++i)
        #pragma unroll
        for (int j = 0; j < 4; ++j) acc[i][j] = zero;

    hfrag rA0, rA1, rB0, rB1;
    #define G2_LOAD(K0)                                   \
        rA0 = *(const hfrag*)(A + aoff0 + (K0));          \
        rA1 = *(const hfrag*)(A + aoff1 + (K0));          \
        rB0 = *(const hfrag*)(B + boff0 + (K0));          \
        rB1 = *(const hfrag*)(B + boff1 + (K0));

    G2_LOAD(0)
    for (int k0 = 0; k0 < MIDC; k0 += 32) {
        *(hfrag*)&Asm[r0][kc] = rA0;
        *(hfrag*)&Asm[r1][kc] = rA1;
        *(hfrag*)&Bsm[r0][kc] = rB0;
        *(hfrag*)&Bsm[r1][kc] = rB1;
        __syncthreads();
        if (k0 + 32 < MIDC) { G2_LOAD(k0 + 32) }
        hfrag bh[4];
        #pragma unroll
        for (int ni = 0; ni < 4; ++ni)
            bh[ni] = *(const hfrag*)&Bsm[wr + ni * 16 + ln][kg * 8];
        #pragma unroll
        for (int mi = 0; mi < 4; ++mi) {
            hfrag a = *(const hfrag*)&Asm[wc + mi * 16 + ln][kg * 8];
            #pragma unroll
            for (int ni = 0; ni < 4; ++ni)
                acc[mi][ni] = __builtin_amdgcn_mfma_f32_16x16x32_f16(a, bh[ni], acc[mi][ni], 0, 0, 0);
        }
        __syncthreads();
    }
    #undef G2_LOAD

    #pragma unroll
    for (int ni = 0; ni < 4; ++ni) {
        int R = R0 + wr + ni * 16 + ln;
        int b = R / HW;
        int n = R - b * HW;
        float* arow = aout + (size_t)b * INC * HW + n;
        #pragma unroll
        for (int mi = 0; mi < 4; ++mi) {
            int cb = C0 + wc + mi * 16 + kg * 4;
            float wv[4];
            *(float4*)wv = *(const float4*)(wb + cb);
            #pragma unroll
            for (int r = 0; r < 4; ++r)
                arow[(size_t)(cb + r) * HW] = acc[mi][ni][r] + wv[r];
        }
    }
}

// ---------------- per-(b,c) row: radix-select v6 ----------------------------
// R6's v3 structure (4 sub-histograms, 264-int stride, 16.9 KB LDS) + -INF
// pads with compile-time slot predication, unpredicated mask/max, and
// pad-corrected exp-sum. Latency-bound at ~60 us — confirmed plateau.
__global__ __launch_bounds__(256) void topk_softmax_reduce(const float* __restrict__ x,
                                                           float* __restrict__ out) {
    const int wid  = threadIdx.x >> 6;
    const int lane = threadIdx.x & 63;
    const int row  = blockIdx.x * 4 + wid;
    float* arow = out + BATCH * INC + (size_t)row * HW;
    const float* xrow = x + (size_t)row * HW;

    __shared__ int hist[4][4][264];   // [wave][subgroup][bin(+pad)] = 16.9 KB
    int* hp0 = &hist[wid][0][0];
    const int g = lane >> 4;          // quarter-wave subgroup

    const bool has3 = (lane < 4);
    float4 v4[4];
    uint32_t key[16];

    {   // vectorized load of the row (196 float4 chunks)
        const float4* ap = (const float4*)arow;
        v4[0] = ap[lane];
        v4[1] = ap[lane + 64];
        v4[2] = ap[lane + 128];
        v4[3] = has3 ? ap[192 + lane]
                     : make_float4(-INFINITY, -INFINITY, -INFINITY, -INFINITY);
    }
    const float* vv = (const float*)v4;
    #pragma unroll
    for (int i = 0; i < 16; ++i) {
        uint32_t uu = __float_as_uint(vv[i]);
        key[i] = (uu & 0x80000000u) ? ~uu : (uu | 0x80000000u);
    }

    int kk = KSEL;
    uint32_t prefix = 0;
    uint32_t thkey = 0;
    bool done = false;

    #pragma unroll
    for (int round = 0; round < 4; ++round) {
        if (!done) {
            const int shift = 24 - 8 * round;
            const int4 z4 = {0, 0, 0, 0};
            if (round == 0) {
                #pragma unroll
                for (int j = 0; j < 5; ++j) {
                    int idx = lane + 64 * j;
                    if (idx < 264) ((int4*)hp0)[idx] = z4;   // zero all 4*264 ints
                }
                #pragma unroll
                for (int i = 0; i < 12; ++i)
                    atomicAdd(&hist[wid][g][key[i] >> 24], 1);
                if (has3) {
                    #pragma unroll
                    for (int i = 12; i < 16; ++i)
                        atomicAdd(&hist[wid][g][key[i] >> 24], 1);
                }
            } else {
                ((int4*)hp0)[lane] = z4;      // zero bins 0..255
                const uint32_t himask = 0xFFFFFFFFu << (shift + 8);
                #pragma unroll
                for (int i = 0; i < 16; ++i)
                    if ((i < 12 || has3) && (key[i] & himask) == prefix)
                        atomicAdd(&hp0[(key[i] >> shift) & 255], 1);
            }

            int h0, h1, h2, h3;
            if (round == 0) {
                int4 c0 = *(const int4*)&hist[wid][0][4 * lane];
                int4 c1 = *(const int4*)&hist[wid][1][4 * lane];
                int4 c2 = *(const int4*)&hist[wid][2][4 * lane];
                int4 c3 = *(const int4*)&hist[wid][3][4 * lane];
                h0 = c0.x + c1.x + c2.x + c3.x;
                h1 = c0.y + c1.y + c2.y + c3.y;
                h2 = c0.z + c1.z + c2.z + c3.z;
                h3 = c0.w + c1.w + c2.w + c3.w;
            } else {
                int4 c = *(const int4*)&hp0[4 * lane];
                h0 = c.x; h1 = c.y; h2 = c.z; h3 = c.w;
            }
            int gsum = h0 + h1 + h2 + h3;
            int suf = gsum;
            #pragma unroll
            for (int off = 1; off < 64; off <<= 1) {
                int o = __shfl_down(suf, off, 64);
                suf += (lane + off < 64) ? o : 0;
            }
            int ex = suf - gsum;
            int cgt3 = ex, cgt2 = cgt3 + h3, cgt1 = cgt2 + h2, cgt0 = cgt1 + h1;
            int bsel = -1, cg = 0, hs = 0;
            if (cgt0 < kk && kk <= cgt0 + h0) { bsel = 4 * lane + 0; cg = cgt0; hs = h0; }
            if (cgt1 < kk && kk <= cgt1 + h1) { bsel = 4 * lane + 1; cg = cgt1; hs = h1; }
            if (cgt2 < kk && kk <= cgt2 + h2) { bsel = 4 * lane + 2; cg = cgt2; hs = h2; }
            if (cgt3 < kk && kk <= cgt3 + h3) { bsel = 4 * lane + 3; cg = cgt3; hs = h3; }
            unsigned long long m = __ballot(bsel >= 0);
            int src = (int)__ffsll((long long)m) - 1;
            bsel = __shfl(bsel, src, 64);
            cg   = __shfl(cg,   src, 64);
            hs   = __shfl(hs,   src, 64);
            kk -= cg;
            prefix |= ((uint32_t)bsel) << shift;

            if (shift == 0) {
                thkey = prefix;
                done = true;
            } else if (kk == 1 || kk == hs) {
                const uint32_t maskP = 0xFFFFFFFFu << shift;
                bool want_max = (kk == 1);
                uint32_t r = want_max ? 0u : 0xFFFFFFFFu;
                #pragma unroll
                for (int i = 0; i < 16; ++i) {
                    if ((i < 12 || has3) && (key[i] & maskP) == prefix)
                        r = want_max ? (r > key[i] ? r : key[i])
                                     : (r < key[i] ? r : key[i]);
                }
                #pragma unroll
                for (int off = 32; off; off >>= 1) {
                    uint32_t o = __shfl_xor(r, off, 64);
                    r = want_max ? (r > o ? r : o) : (r < o ? r : o);
                }
                thkey = r;
                done = true;
            }
        }
    }

    uint32_t tu = (thkey & 0x80000000u) ? (thkey ^ 0x80000000u) : ~thkey;
    const float th = __uint_as_float(tu);

    // mask + max (pads: -INF < th -> 0, exactly like real masked values)
    float* vw = (float*)v4;
    float mx = -INFINITY;
    #pragma unroll
    for (int i = 0; i < 16; ++i) {
        float f = vw[i];
        f = (f < th) ? 0.0f : f;
        vw[i] = f;
        mx = fmaxf(mx, f);
    }
    #pragma unroll
    for (int off = 32; off; off >>= 1) mx = fmaxf(mx, __shfl_xor(mx, off, 64));

    // exp + sum (unpredicated; subtract the 240 pad contributions of e^{-mx})
    float sum = 0.f;
    #pragma unroll
    for (int i = 0; i < 16; ++i) {
        float e = __expf(vw[i] - mx);
        vw[i] = e;
        sum += e;
    }
    #pragma unroll
    for (int off = 32; off; off >>= 1) sum += __shfl_xor(sum, off, 64);
    sum -= 240.0f * __expf(0.0f - mx);
    float inv = 1.0f / sum;

    // normalize + store atten + weighted reduce against x
    float dot = 0.f;
    {
        float4* ap = (float4*)arow;
        const float4* xp = (const float4*)xrow;
        #pragma unroll
        for (int ci = 0; ci < 4; ++ci) {
            if (ci == 3 && !has3) break;
            int chunk = (ci < 3) ? (lane + 64 * ci) : (192 + lane);
            float4 a;
            a.x = vw[ci * 4 + 0] * inv;
            a.y = vw[ci * 4 + 1] * inv;
            a.z = vw[ci * 4 + 2] * inv;
            a.w = vw[ci * 4 + 3] * inv;
            ap[chunk] = a;
            float4 xl = xp[chunk];
            dot += xl.x * a.x + xl.y * a.y + xl.z * a.z + xl.w * a.w;
        }
    }
    #pragma unroll
    for (int off = 32; off; off >>= 1) dot += __shfl_xor(dot, off, 64);
    if (lane == 0) out[row] = dot;
}

extern "C" void kernel_launch(void* const* d_in, const int* in_sizes, int n_in,
                              void* d_out, int out_size, void* d_ws, size_t ws_size,
                              hipStream_t stream) {
    const float* x    = (const float*)d_in[0];
    const float* s    = (const float*)d_in[1];
    const float* Wq_w = (const float*)d_in[2];
    const float* Wq_b = (const float*)d_in[3];
    const float* Uq_w = (const float*)d_in[4];
    const float* w_w  = (const float*)d_in[5];
    const float* w_b  = (const float*)d_in[6];
    float* out = (float*)d_out;

    f16* xt   = (f16*)d_ws;                                   // [25088][1024]
    f16* sig  = xt + (size_t)ROWS * INC;                      // [25088][256]
    f16* wq_h = sig + (size_t)ROWS * MIDC;                    // [256][1024]
    f16* ww_h = wq_h + MIDC * INC;                            // [1024][256]
    float* u  = (float*)(ww_h + INC * MIDC);                  // [32][256]
    float* alpha = out + BATCH * INC;                         // staged in atten slot

    prep_all<<<26144, 256, 0, stream>>>(x, Wq_w, w_w, s, Uq_w, Wq_b,
                                        xt, wq_h, ww_h, u);
    gemm1_mfma<<<dim3(ROWS / 128, 2), 256, 0, stream>>>(wq_h, xt, u, sig);
    gemm2_mfma<<<dim3(ROWS / 128, 8), 256, 0, stream>>>(ww_h, sig, w_b, alpha);
    topk_softmax_reduce<<<BATCH * INC / 4, 256, 0, stream>>>(x, out);
}